// Round 16
// baseline (54.193 us; speedup 1.0000x reference)
//
#include <hip/hip_runtime.h>

// input x: (B=256,T=600,J=25,C=3) f32; x[b,tt,n*5+p,c] = in[(b*600+tt)*75 + n*15 + p*3 + c]
// output: (B,5,1800,4,4) f32, 3 window groups g: tout = g*600+tt.
//
// R16 = R15 dedup (37.9us) + pipelined stage. Grid 768 (3 blocks/CU, persistent);
// block = (b, 200-tt segment) = 4 chunks of 50. Next chunk's global loads issue
// BEFORE compute (in flight across compute+store), ds-committed AFTER the store
// sweep (vmcnt wait lands post-store-issue). Single raw buffer (commit is
// post-barrier). Stage base rounded to 4-row boundary -> all b128 aligned.

#define T_ 600

typedef float fx4 __attribute__((ext_vector_type(4)));

// LDS-only barrier: order LDS ops but let global stores stay in flight.
#define BAR_LDS() do { asm volatile("s_waitcnt lgkmcnt(0)" ::: "memory"); \
                       __builtin_amdgcn_s_barrier(); } while (0)

__device__ __forceinline__ void chunkgeo(int tc, int& sp, int& tot) {
    int s = (tc == 0) ? 0 : ((tc - 1) & ~3);   // 4-row aligned => 16B-aligned floats
    int e = tc + 51; if (e > T_) e = T_;
    sp = s; tot = (e - s) * 75;
}

__global__ __launch_bounds__(256) void gauss_agg_kernel(const float* __restrict__ x,
                                                        float* __restrict__ out) {
    __shared__ float raw[4128];        // up to 55 rows * 75 floats, 16.5 KB
    __shared__ float4 obuf[256 * 5];   // 20 KB; 80B/slot stride avoids bank aliasing

    int blk = blockIdx.x;              // 768 = 256 b * 3 segments
    int seg = blk % 3;
    int b   = blk / 3;
    int tid = (int)threadIdx.x;

    const float* xb = x + (size_t)b * 45000;
    fx4* outf4 = reinterpret_cast<fx4*>(out);
    const float w5[5] = {4.f, 2.f, 3.f, 2.f, 4.f};
    float4* rawv = reinterpret_cast<float4*>(raw);

    float4 v[5]; float vt = 0.f;

    // ---- prologue: stage chunk 0 ----
    {
        int sp, tot; chunkgeo(seg * 200, sp, tot);
        int nv = tot >> 2, tail = tot & 3;
        const float4* srcv = reinterpret_cast<const float4*>(xb + (size_t)sp * 75);
        #pragma unroll
        for (int i = 0; i < 5; ++i) { int e = i * 256 + tid; if (e < nv) v[i] = srcv[e]; }
        if (tid < tail) vt = xb[(size_t)sp * 75 + nv * 4 + tid];
        #pragma unroll
        for (int i = 0; i < 5; ++i) { int e = i * 256 + tid; if (e < nv) rawv[e] = v[i]; }
        if (tid < tail) raw[nv * 4 + tid] = vt;
    }
    BAR_LDS();

    for (int c = 0; c < 4; ++c) {
        int tc = seg * 200 + c * 50;
        int cg = tc / 50;                 // global chunk id 0..11

        // window-boundary tt inside this chunk (at most one)
        int vtt = -1;
        switch (cg) {
            case 0:  vtt = 0;   break;  case 3:  vtt = 199; break;
            case 4:  vtt = 200; break;  case 5:  vtt = 299; break;
            case 6:  vtt = 300; break;  case 7:  vtt = 399; break;
            case 8:  vtt = 400; break;  case 11: vtt = 599; break;
            default: break;
        }

        int sp, tot; chunkgeo(tc, sp, tot);
        int lofs = tc - sp;

        // ---- issue next chunk's loads NOW (complete during compute+store) ----
        int nsp = 0, ntot = 0, nnv = 0, ntail = 0;
        if (c < 3) {
            chunkgeo(tc + 50, nsp, ntot);
            nnv = ntot >> 2; ntail = ntot & 3;
            const float4* srcv = reinterpret_cast<const float4*>(xb + (size_t)nsp * 75);
            #pragma unroll
            for (int i = 0; i < 5; ++i) { int e = i * 256 + tid; if (e < nnv) v[i] = srcv[e]; }
            if (tid < ntail) vt = xb[(size_t)nsp * 75 + nnv * 4 + tid];
        }

        // ---- compute: ONE batch of 255 unique slots ----
        {
            bool isvar = (tid >= 250);
            int n, tt;
            if (!isvar) { n = tid / 50; tt = tc + (tid - n * 50); }
            else        { int k = tid - 250; n = (k > 4) ? 4 : k; tt = (vtt < 0) ? tc : vtt; }
            int li = (tt - tc) + lofs;
            int lp = li - 1; if (lp < 0) lp = 0;   // only tc==0,tt==0 (result unused)
            int ln = li + 1;                        // may read junk for tt==599 (unused)

            const float* rc = &raw[li * 75 + n * 15];

            float s0=0.f,s1=0.f,s2=0.f, m0=0.f,m1=0.f,m2=0.f;
            float A00=0.f,A01=0.f,A02=0.f,A11=0.f,A12=0.f,A22=0.f;
            #pragma unroll
            for (int p = 0; p < 5; ++p) {
                float a = rc[p*3+0], cc = rc[p*3+1], d = rc[p*3+2];
                s0 += a; s1 += cc; s2 += d;
                m0 += w5[p]*a; m1 += w5[p]*cc; m2 += w5[p]*d;
                A00 += a*a; A01 += a*cc; A02 += a*d;
                A11 += cc*cc; A12 += cc*d; A22 += d*d;
            }
            float mu0 = m0*(1.f/15.f), mu1 = m1*(1.f/15.f), mu2 = m2*(1.f/15.f);

            float inv = 0.2f;
            if (!isvar) {
                const float* r0 = &raw[lp * 75 + n * 15];
                const float* r1 = &raw[ln * 75 + n * 15];
                #pragma unroll
                for (int dstep = 0; dstep < 2; ++dstep) {
                    const float* rn = dstep ? r1 : r0;
                    #pragma unroll
                    for (int p = 0; p < 5; ++p) {
                        float a = rn[p*3+0], cc = rn[p*3+1], d = rn[p*3+2];
                        s0 += a; s1 += cc; s2 += d;
                        A00 += a*a; A01 += a*cc; A02 += a*d;
                        A11 += cc*cc; A12 += cc*d; A22 += d*d;
                    }
                }
                inv = 1.f/15.f;
            }

            float mb0 = s0*inv, mb1 = s1*inv, mb2 = s2*inv;
            float e00 = A00*inv - 2.f*mu0*mb0 + 2.f*mu0*mu0;
            float e01 = A01*inv - mu0*mb1 - mb0*mu1 + 2.f*mu0*mu1;
            float e02 = A02*inv - mu0*mb2 - mb0*mu2 + 2.f*mu0*mu2;
            float e11 = A11*inv - 2.f*mu1*mb1 + 2.f*mu1*mu1;
            float e12 = A12*inv - mu1*mb2 - mb1*mu2 + 2.f*mu1*mu2;
            float e22 = A22*inv - 2.f*mu2*mb2 + 2.f*mu2*mu2;

            int base = tid * 5;
            obuf[base + 0] = make_float4(e00, e01, e02, mu0);
            obuf[base + 1] = make_float4(e01, e11, e12, mu1);
            obuf[base + 2] = make_float4(e02, e12, e22, mu2);
            obuf[base + 3] = make_float4(mu0, mu1, mu2, 1.f);
        }
        BAR_LDS();

        // ---- store: 750 slots x 4 pieces, lane-contiguous nontemporal ----
        #pragma unroll
        for (int k = 0; k < 12; ++k) {
            int f = k * 256 + tid;
            if (f < 3000) {
                int sl = f >> 2, pc = f & 3;
                int n  = sl / 150;
                int q  = sl - n * 150;
                int w  = q / 50;
                int tl = q - w * 50;
                int tt = tc + tl;
                bool bd;
                if (w == 0)      bd = (tt == 0) || (tt == 599);
                else if (w == 1) { int r = tt % 300; bd = (r == 0) || (r == 299); }
                else             { int r = tt % 200; bd = (r == 0) || (r == 199); }
                int oi = bd ? (250 + n) : (n * 50 + tl);
                size_t o = ((size_t)(b * 5 + n) * 1800 + w * 600 + tt) * 4 + pc;
                float4 vv = obuf[oi * 5 + pc];
                fx4 nv4; nv4.x = vv.x; nv4.y = vv.y; nv4.z = vv.z; nv4.w = vv.w;
                __builtin_nontemporal_store(nv4, &outf4[o]);
            }
        }

        // ---- commit next chunk (loads have had compute+store to land) ----
        if (c < 3) {
            #pragma unroll
            for (int i = 0; i < 5; ++i) { int e = i * 256 + tid; if (e < nnv) rawv[e] = v[i]; }
            if (tid < ntail) raw[nnv * 4 + tid] = vt;
        }
        BAR_LDS();
    }
}

extern "C" void kernel_launch(void* const* d_in, const int* in_sizes, int n_in,
                              void* d_out, int out_size, void* d_ws, size_t ws_size,
                              hipStream_t stream) {
    const float* x = (const float*)d_in[0];
    float* out = (float*)d_out;
    gauss_agg_kernel<<<768, 256, 0, stream>>>(x, out);
}

// Round 17
// 37.460 us; speedup vs baseline: 1.4467x; 1.4467x over previous
//
#include <hip/hip_runtime.h>

// input x: (B=256,T=600,J=25,C=3) f32; x[b,tt,n*5+p,c] = in[(b*600+tt)*75 + n*15 + p*3 + c]
// output: (B,5,1800,4,4) f32, 3 window groups g: tout = g*600+tt.
//
// R17 = R15 dedup structure scaled to CH=100 with 512-thread blocks:
// 1536 blocks (half the cold-starts/retire-drains), 6.4KB write runs.
// Unique work per chunk = 500 interior + 5*(#boundary tts in chunk, <=2) <= 510
// -> ONE compute batch. raw 30.6KB + obuf 40KB (stride-5 pad) = 70.6KB LDS
// -> 2 blocks/CU = 16 waves/CU (same as R15). nt stores, lgkm-only barriers.

#define T_ 600
#define CH_ 100
#define NCH_ 6

typedef float fx4 __attribute__((ext_vector_type(4)));

// LDS-only barrier: order LDS ops but let global stores stay in flight.
#define BAR_LDS() do { asm volatile("s_waitcnt lgkmcnt(0)" ::: "memory"); \
                       __builtin_amdgcn_s_barrier(); } while (0)

__global__ __launch_bounds__(512) void gauss_agg_kernel(const float* __restrict__ x,
                                                        float* __restrict__ out) {
    // raw: [0,7500) rows tc..tc+99; [7500,7575) row tc-1; [7575,7650) row tc+100
    __shared__ float raw[7650];        // 30.6 KB
    __shared__ float4 obuf[512 * 5];   // 40 KB; 80B/slot stride avoids bank degeneracy

    int blk = blockIdx.x;
    int ch  = blk % NCH_;
    int b   = blk / NCH_;
    int tc  = ch * CH_;
    int tid = (int)threadIdx.x;

    // window-boundary tts inside this chunk (up to two)
    int vtt1 = -1, vtt2 = -1;
    switch (ch) {
        case 0: vtt1 = 0;   break;
        case 1: vtt1 = 199; break;
        case 2: vtt1 = 200; vtt2 = 299; break;
        case 3: vtt1 = 300; vtt2 = 399; break;
        case 4: vtt1 = 400; break;
        case 5: vtt1 = 599; break;
    }

    // ---- stage: main 100 rows vectorized (16B-aligned: (b*600+tc)*75 % 4 == 0), halo scalar ----
    {
        const float4* srcv = reinterpret_cast<const float4*>(x + ((size_t)b * T_ + tc) * 75);
        float4* rawv = reinterpret_cast<float4*>(raw);
        #pragma unroll
        for (int i = 0; i < 4; ++i) {
            int e = i * 512 + tid;
            if (e < 1875) rawv[e] = srcv[e];
        }
        if (tid < 150) {
            int rp  = (tid < 75) ? (tc > 0 ? tc - 1 : 0)
                                 : (tc + CH_ < T_ ? tc + CH_ : T_ - 1);
            int col = (tid < 75) ? tid : tid - 75;
            raw[7500 + tid] = x[((size_t)b * T_ + rp) * 75 + col];
        }
    }
    BAR_LDS();

    const float w5[5] = {4.f, 2.f, 3.f, 2.f, 4.f};
    fx4* outf4 = reinterpret_cast<fx4*>(out);

    // ---- compute: ONE batch of 510 unique slots ----
    if (tid < 510) {
        bool isvar = (tid >= 500);
        int n, tt;
        if (!isvar) { n = tid / 100; tt = tc + (tid - n * 100); }
        else if (tid < 505) { n = tid - 500; tt = (vtt1 < 0) ? tc : vtt1; }
        else                { n = tid - 505; tt = (vtt2 < 0) ? tc : vtt2; }
        int tl = tt - tc;

        int midoff = tl * 75 + n * 15;
        const float* rc = &raw[midoff];
        // neighbor rows via halo tail at chunk edges (global-edge tts are boundary
        // slots whose interior path is never used)
        const float* r0 = &raw[(tl == 0)  ? 7500 + n * 15 : midoff - 75];
        const float* r1 = &raw[(tl == 99) ? 7575 + n * 15 : midoff + 75];

        float s0=0.f,s1=0.f,s2=0.f, m0=0.f,m1=0.f,m2=0.f;
        float A00=0.f,A01=0.f,A02=0.f,A11=0.f,A12=0.f,A22=0.f;
        #pragma unroll
        for (int p = 0; p < 5; ++p) {
            float a = rc[p*3+0], c = rc[p*3+1], d = rc[p*3+2];
            s0 += a; s1 += c; s2 += d;
            m0 += w5[p]*a; m1 += w5[p]*c; m2 += w5[p]*d;
            A00 += a*a; A01 += a*c; A02 += a*d;
            A11 += c*c; A12 += c*d; A22 += d*d;
        }
        float mu0 = m0*(1.f/15.f), mu1 = m1*(1.f/15.f), mu2 = m2*(1.f/15.f);

        float inv = 0.2f;
        if (!isvar) {
            #pragma unroll
            for (int dstep = 0; dstep < 2; ++dstep) {
                const float* rn = dstep ? r1 : r0;
                #pragma unroll
                for (int p = 0; p < 5; ++p) {
                    float a = rn[p*3+0], c = rn[p*3+1], d = rn[p*3+2];
                    s0 += a; s1 += c; s2 += d;
                    A00 += a*a; A01 += a*c; A02 += a*d;
                    A11 += c*c; A12 += c*d; A22 += d*d;
                }
            }
            inv = 1.f/15.f;
        }

        float mb0 = s0*inv, mb1 = s1*inv, mb2 = s2*inv;
        float e00 = A00*inv - 2.f*mu0*mb0 + 2.f*mu0*mu0;
        float e01 = A01*inv - mu0*mb1 - mb0*mu1 + 2.f*mu0*mu1;
        float e02 = A02*inv - mu0*mb2 - mb0*mu2 + 2.f*mu0*mu2;
        float e11 = A11*inv - 2.f*mu1*mb1 + 2.f*mu1*mu1;
        float e12 = A12*inv - mu1*mb2 - mb1*mu2 + 2.f*mu1*mu2;
        float e22 = A22*inv - 2.f*mu2*mb2 + 2.f*mu2*mu2;

        int base = tid * 5;
        obuf[base + 0] = make_float4(e00, e01, e02, mu0);
        obuf[base + 1] = make_float4(e01, e11, e12, mu1);
        obuf[base + 2] = make_float4(e02, e12, e22, mu2);
        obuf[base + 3] = make_float4(mu0, mu1, mu2, 1.f);
    }
    BAR_LDS();

    // ---- store: 1500 slots x 4 pieces, lane-contiguous nontemporal ----
    #pragma unroll
    for (int k = 0; k < 12; ++k) {
        int f = k * 512 + tid;
        if (f < 6000) {
            int sl = f >> 2, pc = f & 3;
            int n  = sl / 300;
            int q  = sl - n * 300;
            int w  = q / 100;
            int tl = q - w * 100;
            int tt = tc + tl;
            bool bd;
            if (w == 0)      bd = (tt == 0) || (tt == 599);
            else if (w == 1) { int r = tt % 300; bd = (r == 0) || (r == 299); }
            else             { int r = tt % 200; bd = (r == 0) || (r == 199); }
            int oi;
            if (!bd)             oi = n * 100 + tl;
            else if (tt == vtt1) oi = 500 + n;
            else                 oi = 505 + n;
            size_t o = ((size_t)(b * 5 + n) * 1800 + w * 600 + tt) * 4 + pc;
            float4 v = obuf[oi * 5 + pc];
            fx4 nv; nv.x = v.x; nv.y = v.y; nv.z = v.z; nv.w = v.w;
            __builtin_nontemporal_store(nv, &outf4[o]);
        }
    }
}

extern "C" void kernel_launch(void* const* d_in, const int* in_sizes, int n_in,
                              void* d_out, int out_size, void* d_ws, size_t ws_size,
                              hipStream_t stream) {
    const float* x = (const float*)d_in[0];
    float* out = (float*)d_out;
    gauss_agg_kernel<<<256 * NCH_, 512, 0, stream>>>(x, out);
}